// Round 2
// baseline (175.663 us; speedup 1.0000x reference)
//
#include <hip/hip_runtime.h>
#include <hip/hip_bf16.h>
#include <math.h>

// out[b,i,p] = sqrt(yr^2+yi^2); yr/yi = (Hr/Hi[b] @ x[b])*scale + noise*0.01
// B=32, C=256, P=3136. Memory-bound: HBM floor ~61us (noise 206MB + out 103MB
// + x/H). Round-2: async x staging (global_load_lds, 2-phase, 1 barrier/iter),
// H pre-converted to bf16 (frags straight from L2, no H LDS), swizzled x reads,
// NT epilogue, XCD-chunked block swizzle.

#define NBATCH 32
#define NC 256
#define NP 3136
#define BM 128
#define BN 64
#define BK 32
#define NBN 49
#define NKI 8          // 256/32 K-steps

typedef __attribute__((ext_vector_type(8))) short short8;
typedef __attribute__((ext_vector_type(4))) float f32x4;

static __device__ __forceinline__ void gload16(const void* g, void* l) {
  __builtin_amdgcn_global_load_lds(
      (const __attribute__((address_space(1))) void*)g,
      (__attribute__((address_space(3))) void*)l, 16, 0, 0);
}

static __device__ __forceinline__ unsigned short bfr(float f) {
  __hip_bfloat16 h = __float2bfloat16(f);   // RNE; compiler pairs into v_cvt_pk_bf16_f32
  return *reinterpret_cast<unsigned short*>(&h);
}

// ---- pre-pass: Hr/Hi fp32 -> bf16 in workspace (2 x 2,097,152 elems) ----
__global__ __launch_bounds__(256)
void cvt_h_kernel(const float* __restrict__ hr, const float* __restrict__ hi,
                  unsigned short* __restrict__ hrb, unsigned short* __restrict__ hib)
{
  const size_t i4 = ((size_t)blockIdx.x * 256 + threadIdx.x) * 4;
  const float4 r = *reinterpret_cast<const float4*>(hr + i4);
  const float4 s = *reinterpret_cast<const float4*>(hi + i4);
  union { uint2 v; unsigned short u[4]; } o1, o2;
  o1.u[0] = bfr(r.x); o1.u[1] = bfr(r.y); o1.u[2] = bfr(r.z); o1.u[3] = bfr(r.w);
  o2.u[0] = bfr(s.x); o2.u[1] = bfr(s.y); o2.u[2] = bfr(s.z); o2.u[3] = bfr(s.w);
  *reinterpret_cast<uint2*>(hrb + i4) = o1.v;
  *reinterpret_cast<uint2*>(hib + i4) = o2.v;
}

// x LDS physical layout: fp32 [k 0..31][p 0..63], byte_phys = byte_log ^ X(k),
// X(k) = ((fq&1)<<6)|((fq>>1)<<4), fq=k>>3. Touches only byte bits {4,6} (16B
// granules) -> compatible with linear global_load_lds dest via pre-swizzled
// per-lane SOURCE (rule #21). Column reads then land max-2-way per bank (free).
template<int PRE>
__global__ __launch_bounds__(256)
void rayleigh_main(const float* __restrict__ xg,
                   const float* __restrict__ Hrg,
                   const float* __restrict__ Hig,
                   const unsigned short* __restrict__ Hrb,
                   const unsigned short* __restrict__ Hib,
                   const float* __restrict__ nrg,
                   const float* __restrict__ nig,
                   float* __restrict__ outg)
{
  __shared__ float x_lds[2][BK * BN];   // 2 x 8KB double buffer

  // XCD-chunked bijection: 3136 = 8*392; each XCD gets a contiguous slab
  // (~4 batches) -> H(bf16)+x stay L2-resident per XCD.
  const int raw = blockIdx.x;
  const int v   = (raw & 7) * 392 + (raw >> 3);
  const int b   = v / 98;
  const int r2  = v - b * 98;
  const int bm  = r2 / 49;
  const int bn  = r2 - bm * 49;

  const int tid  = threadIdx.x;
  const int lane = tid & 63;
  const int wave = tid >> 6;      // 4 waves: 2(M) x 2(N)
  const int wm   = wave >> 1;
  const int wn   = wave & 1;
  const int fr   = lane & 15;
  const int fq   = lane >> 4;

  const float* xsrc = xg + (size_t)b * NC * NP + (size_t)bn * BN;
  const int w2 = wave * 2;

  // stage one 32x64 fp32 x-tile: 8 DMA chunks of 1KB, wave w does chunks 2w,2w+1
  auto stage = [&](float* buf, int kt) {
    #pragma unroll
    for (int i = 0; i < 2; ++i) {
      const int C16 = (w2 + i) * 64 + lane;     // 16B chunk index in 8KB buffer
      const int k   = C16 >> 4;                 // row (k within tile)
      const int cp  = C16 & 15;                 // physical 16B chunk within row
      const int fqk = k >> 3;
      const int cl  = cp ^ (((fqk & 1) << 2) | (fqk >> 1));  // logical chunk
      const float* src = xsrc + (size_t)(kt * BK + k) * NP + cl * 4;
      void* dst = (char*)buf + (w2 + i) * 1024; // wave-uniform LDS base
      gload16(src, dst);
    }
  };

  f32x4 accR[4][2], accI[4][2];
  #pragma unroll
  for (int m = 0; m < 4; ++m)
    #pragma unroll
    for (int n = 0; n < 2; ++n) {
      accR[m][n] = (f32x4){0.f, 0.f, 0.f, 0.f};
      accI[m][n] = (f32x4){0.f, 0.f, 0.f, 0.f};
    }

  const size_t hrow = (size_t)b * NC + bm * BM + wm * 64 + fr;
  const unsigned short* hrb = Hrb + hrow * NC + fq * 8;
  const unsigned short* hib = Hib + hrow * NC + fq * 8;
  const float* hrf = Hrg + hrow * NC + fq * 8;
  const float* hif = Hig + hrow * NC + fq * 8;
  const int xork = ((fq & 1) << 6) | ((fq >> 1) << 4);
  const int pb   = wn * 32 + fr;

  stage(x_lds[0], 0);

  #pragma unroll
  for (int t = 0; t < NKI; ++t) {
    __syncthreads();                    // drains DMA: buf[t&1] ready
    if (t + 1 < NKI) stage(x_lds[(t + 1) & 1], t + 1);  // in flight all iter
    const int k0 = t * BK;
    const char* xbuf = (const char*)x_lds[t & 1];

    // B-fragments: 16 swizzled ds_read_b32 + pk-convert to bf16
    short8 xb[2];
    #pragma unroll
    for (int n = 0; n < 2; ++n) {
      const int pcol = ((pb + n * 16) << 2) ^ xork;
      union { short8 s; unsigned short u[8]; } u;
      #pragma unroll
      for (int j = 0; j < 8; ++j) {
        const float f = *reinterpret_cast<const float*>(xbuf + ((fq * 8 + j) << 8) + pcol);
        u.u[j] = bfr(f);
      }
      xb[n] = u.s;
    }

    // A-fragments straight from global (L2-hot bf16), then MFMA
    #pragma unroll
    for (int m = 0; m < 4; ++m) {
      short8 ar, ai;
      if constexpr (PRE) {
        ar = *reinterpret_cast<const short8*>(hrb + (size_t)m * 16 * NC + k0);
        ai = *reinterpret_cast<const short8*>(hib + (size_t)m * 16 * NC + k0);
      } else {
        const float* p1 = hrf + (size_t)m * 16 * NC + k0;
        const float* p2 = hif + (size_t)m * 16 * NC + k0;
        const float4 v0 = *reinterpret_cast<const float4*>(p1);
        const float4 v1 = *reinterpret_cast<const float4*>(p1 + 4);
        const float4 w0 = *reinterpret_cast<const float4*>(p2);
        const float4 w1 = *reinterpret_cast<const float4*>(p2 + 4);
        union { short8 s; unsigned short u[8]; } a1, a2;
        a1.u[0] = bfr(v0.x); a1.u[1] = bfr(v0.y); a1.u[2] = bfr(v0.z); a1.u[3] = bfr(v0.w);
        a1.u[4] = bfr(v1.x); a1.u[5] = bfr(v1.y); a1.u[6] = bfr(v1.z); a1.u[7] = bfr(v1.w);
        a2.u[0] = bfr(w0.x); a2.u[1] = bfr(w0.y); a2.u[2] = bfr(w0.z); a2.u[3] = bfr(w0.w);
        a2.u[4] = bfr(w1.x); a2.u[5] = bfr(w1.y); a2.u[6] = bfr(w1.z); a2.u[7] = bfr(w1.w);
        ar = a1.s; ai = a2.s;
      }
      #pragma unroll
      for (int n = 0; n < 2; ++n) {
        accR[m][n] = __builtin_amdgcn_mfma_f32_16x16x32_bf16(ar, xb[n], accR[m][n], 0, 0, 0);
        accI[m][n] = __builtin_amdgcn_mfma_f32_16x16x32_bf16(ai, xb[n], accI[m][n], 0, 0, 0);
      }
    }
  }

  // ---- fused epilogue: NT noise loads (issued first), scale+magnitude, NT store
  const float scale = 0.04419417382415922f;  // 1/sqrt(512)
  const float nstd  = 0.01f;
  const size_t obase = ((size_t)b * NC + bm * BM + wm * 64 + fq * 4) * NP
                     + (size_t)bn * BN + wn * 32 + fr;
  float nrv[4][2][4], niv[4][2][4];
  #pragma unroll
  for (int m = 0; m < 4; ++m)
    #pragma unroll
    for (int n = 0; n < 2; ++n)
      #pragma unroll
      for (int r = 0; r < 4; ++r) {
        const size_t idx = obase + (size_t)(m * 16 + r) * NP + n * 16;
        nrv[m][n][r] = __builtin_nontemporal_load(nrg + idx);
        niv[m][n][r] = __builtin_nontemporal_load(nig + idx);
      }
  #pragma unroll
  for (int m = 0; m < 4; ++m)
    #pragma unroll
    for (int n = 0; n < 2; ++n)
      #pragma unroll
      for (int r = 0; r < 4; ++r) {
        const size_t idx = obase + (size_t)(m * 16 + r) * NP + n * 16;
        const float yr = accR[m][n][r] * scale + nrv[m][n][r] * nstd;
        const float yi = accI[m][n][r] * scale + niv[m][n][r] * nstd;
        __builtin_nontemporal_store(sqrtf(yr * yr + yi * yi), outg + idx);
      }
}

extern "C" void kernel_launch(void* const* d_in, const int* in_sizes, int n_in,
                              void* d_out, int out_size, void* d_ws, size_t ws_size,
                              hipStream_t stream) {
  const float* x  = (const float*)d_in[0];
  const float* Hr = (const float*)d_in[1];
  const float* Hi = (const float*)d_in[2];
  const float* nr = (const float*)d_in[3];
  const float* ni = (const float*)d_in[4];
  float* out = (float*)d_out;

  const size_t HN = (size_t)NBATCH * NC * NC;  // 2,097,152 elems per H array

  if (ws_size >= HN * 2 * sizeof(unsigned short)) {
    unsigned short* hrb = (unsigned short*)d_ws;
    unsigned short* hib = hrb + HN;
    hipLaunchKernelGGL(cvt_h_kernel, dim3(2048), dim3(256), 0, stream, Hr, Hi, hrb, hib);
    hipLaunchKernelGGL((rayleigh_main<1>), dim3(NBATCH * 2 * NBN), dim3(256), 0, stream,
                       x, Hr, Hi, hrb, hib, nr, ni, out);
  } else {
    hipLaunchKernelGGL((rayleigh_main<0>), dim3(NBATCH * 2 * NBN), dim3(256), 0, stream,
                       x, Hr, Hi, (const unsigned short*)nullptr, (const unsigned short*)nullptr,
                       nr, ni, out);
  }
}

// Round 3
// 131.434 us; speedup vs baseline: 1.3365x; 1.3365x over previous
//
#include <hip/hip_runtime.h>
#include <hip/hip_bf16.h>
#include <math.h>

// out[b,i,p] = sqrt(yr^2+yi^2); yr/yi = (Hr/Hi[b] @ x[b])*scale + noise*0.01
// B=32, C=256, P=3136. Memory-bound (~450MB compulsory, ~61-71us HBM floor).
// Round-3: H bf16 pre-converted + DMA-staged to LDS (conflict-free [fq][row][8]
// layout), x fp32 DMA dbuf with verified swizzle, noise prefetched into regs
// DURING the K-loop (overlaps the 206MB noise stream with GEMM), 8 waves/block.

#define NBATCH 32
#define NC 256
#define NP 3136
#define BM 128
#define BN 64
#define BK 32
#define NBN 49
#define NKI 8          // 256/32 K-steps

typedef __attribute__((ext_vector_type(8))) short short8;
typedef __attribute__((ext_vector_type(4))) float f32x4;

static __device__ __forceinline__ void gload16(const void* g, void* l) {
  __builtin_amdgcn_global_load_lds(
      (const __attribute__((address_space(1))) void*)g,
      (__attribute__((address_space(3))) void*)l, 16, 0, 0);
}

static __device__ __forceinline__ unsigned short bfr(float f) {
  __hip_bfloat16 h = __float2bfloat16(f);   // RNE; pairs into v_cvt_pk_bf16_f32
  return *reinterpret_cast<unsigned short*>(&h);
}

// ---- pre-pass: Hr/Hi fp32 -> bf16 in workspace (2 x 2,097,152 elems) ----
__global__ __launch_bounds__(256)
void cvt_h_kernel(const float* __restrict__ hr, const float* __restrict__ hi,
                  unsigned short* __restrict__ hrb, unsigned short* __restrict__ hib)
{
  const size_t i4 = ((size_t)blockIdx.x * 256 + threadIdx.x) * 4;
  const float4 r = *reinterpret_cast<const float4*>(hr + i4);
  const float4 s = *reinterpret_cast<const float4*>(hi + i4);
  union { uint2 v; unsigned short u[4]; } o1, o2;
  o1.u[0] = bfr(r.x); o1.u[1] = bfr(r.y); o1.u[2] = bfr(r.z); o1.u[3] = bfr(r.w);
  o2.u[0] = bfr(s.x); o2.u[1] = bfr(s.y); o2.u[2] = bfr(s.z); o2.u[3] = bfr(s.w);
  *reinterpret_cast<uint2*>(hrb + i4) = o1.v;
  *reinterpret_cast<uint2*>(hib + i4) = o2.v;
}

// x LDS: fp32 [k 0..31][p 0..63], phys 16B-chunk = logical ^ swz(k>>3) (verified
// 0 bank conflicts in r2). H LDS: bf16 [fq 0..3][row 0..127][8 elems]: A-read
// ds_read_b128 at fq*2048+row*16 -> within each 16-lane group rows spread over
// 8 distinct 16B slots -> 2-way only (free). DMA dst linear per (fq,half) chunk.
template<int PRE>
__global__ __launch_bounds__(512, 4)
void rayleigh_main(const float* __restrict__ xg,
                   const float* __restrict__ Hrg,
                   const float* __restrict__ Hig,
                   const unsigned short* __restrict__ Hrb,
                   const unsigned short* __restrict__ Hib,
                   const float* __restrict__ nrg,
                   const float* __restrict__ nig,
                   float* __restrict__ outg)
{
  __shared__ float x_lds[2][BK * BN];            // 2 x 8KB
  __shared__ unsigned short hr_lds[2][4096];     // 2 x 8KB  [fq][row][8]
  __shared__ unsigned short hi_lds[2][4096];     // 2 x 8KB

  // XCD-chunked bijection: 3136 = 8*392 = 8 * (4 batches * 98). Each XCD owns
  // 4 whole batches -> x[b] (3.2MB) L2-resident, read from HBM once.
  const int raw = blockIdx.x;
  const int v   = (raw & 7) * 392 + (raw >> 3);
  const int b   = v / 98;
  const int r2  = v - b * 98;
  const int bm  = r2 / 49;
  const int bn  = r2 - bm * 49;

  const int tid  = threadIdx.x;
  const int lane = tid & 63;
  const int wave = tid >> 6;      // 8 waves: 2(M) x 4(N)
  const int wm   = wave >> 2;
  const int wn   = wave & 3;
  const int fr   = lane & 15;
  const int fq   = lane >> 4;

  const float* xsrc = xg + (size_t)b * NC * NP + (size_t)bn * BN;
  const size_t hrowbase = (size_t)b * NC + bm * BM;

  // stage one K-tile: x 8KB (8 chunks, wave w -> chunk w) + hr/hi 8KB each
  // (16 chunks, wave w -> chunks 2w, 2w+1). All async DMA.
  auto stage = [&](int t, int buf) {
    {
      const int C16 = wave * 64 + lane;          // 16B chunk idx in 8KB x-tile
      const int k   = C16 >> 4;
      const int cp  = C16 & 15;
      const int fqk = k >> 3;
      const int cl  = cp ^ (((fqk & 1) << 2) | (fqk >> 1));
      const float* src = xsrc + (size_t)(t * BK + k) * NP + cl * 4;
      gload16(src, (char*)x_lds[buf] + wave * 1024);
    }
    if constexpr (PRE) {
      #pragma unroll
      for (int i = 0; i < 2; ++i) {
        const int c    = wave * 2 + i;           // 0..15
        const unsigned short* hb = (c & 8) ? Hib : Hrb;
        unsigned short* hl = (c & 8) ? hi_lds[buf] : hr_lds[buf];
        const int fqc  = (c >> 1) & 3;
        const int half = c & 1;
        const unsigned short* src =
            hb + (hrowbase + half * 64 + lane) * NC + t * BK + fqc * 8;
        gload16(src, (char*)hl + fqc * 2048 + half * 1024);
      }
    }
  };

  f32x4 accR[4], accI[4];
  #pragma unroll
  for (int m = 0; m < 4; ++m) {
    accR[m] = (f32x4){0.f, 0.f, 0.f, 0.f};
    accI[m] = (f32x4){0.f, 0.f, 0.f, 0.f};
  }
  float nrv[4][4], niv[4][4];

  const size_t obase = ((size_t)b * NC + bm * BM + wm * 64 + fq * 4) * NP
                     + (size_t)bn * BN + wn * 16 + fr;
  const int xork = ((fq & 1) << 6) | ((fq >> 1) << 4);
  const int pcol = ((wn * 16 + fr) << 2) ^ xork;

  stage(0, 0);

  #pragma unroll
  for (int t = 0; t < NKI; ++t) {
    __syncthreads();                       // buffers[t&1] ready (drains DMA)
    if (t + 1 < NKI) stage(t + 1, (t + 1) & 1);

    // noise prefetch chunk t: 4 NT dword loads -> regs (overlaps GEMM phase)
    {
      const int m = t >> 1, rb = (t & 1) * 2;
      #pragma unroll
      for (int r = 0; r < 2; ++r) {
        const size_t idx = obase + (size_t)(m * 16 + rb + r) * NP;
        nrv[m][rb + r] = __builtin_nontemporal_load(nrg + idx);
        niv[m][rb + r] = __builtin_nontemporal_load(nig + idx);
      }
    }

    // B-fragment: 8 swizzled ds_read_b32 + pk-convert (0 bank conflicts, r2)
    const char* xbuf = (const char*)x_lds[t & 1];
    union { short8 s; unsigned short u[8]; } u;
    #pragma unroll
    for (int j = 0; j < 8; ++j) {
      const float f = *reinterpret_cast<const float*>(xbuf + ((fq * 8 + j) << 8) + pcol);
      u.u[j] = bfr(f);
    }
    const short8 xb = u.s;

    // A-fragments from LDS (ds_read_b128, 2-way = free) + MFMA
    #pragma unroll
    for (int m = 0; m < 4; ++m) {
      const int row = wm * 64 + m * 16 + fr;
      short8 ar, ai;
      if constexpr (PRE) {
        ar = *reinterpret_cast<const short8*>(&hr_lds[t & 1][fq * 1024 + row * 8]);
        ai = *reinterpret_cast<const short8*>(&hi_lds[t & 1][fq * 1024 + row * 8]);
      } else {
        const float* p1 = Hrg + (hrowbase + row) * NC + t * BK + fq * 8;
        const float* p2 = Hig + (hrowbase + row) * NC + t * BK + fq * 8;
        const float4 v0 = *reinterpret_cast<const float4*>(p1);
        const float4 v1 = *reinterpret_cast<const float4*>(p1 + 4);
        const float4 w0 = *reinterpret_cast<const float4*>(p2);
        const float4 w1 = *reinterpret_cast<const float4*>(p2 + 4);
        union { short8 s; unsigned short uu[8]; } a1, a2;
        a1.uu[0] = bfr(v0.x); a1.uu[1] = bfr(v0.y); a1.uu[2] = bfr(v0.z); a1.uu[3] = bfr(v0.w);
        a1.uu[4] = bfr(v1.x); a1.uu[5] = bfr(v1.y); a1.uu[6] = bfr(v1.z); a1.uu[7] = bfr(v1.w);
        a2.uu[0] = bfr(w0.x); a2.uu[1] = bfr(w0.y); a2.uu[2] = bfr(w0.z); a2.uu[3] = bfr(w0.w);
        a2.uu[4] = bfr(w1.x); a2.uu[5] = bfr(w1.y); a2.uu[6] = bfr(w1.z); a2.uu[7] = bfr(w1.w);
        ar = a1.s; ai = a2.s;
      }
      accR[m] = __builtin_amdgcn_mfma_f32_16x16x32_bf16(ar, xb, accR[m], 0, 0, 0);
      accI[m] = __builtin_amdgcn_mfma_f32_16x16x32_bf16(ai, xb, accI[m], 0, 0, 0);
    }
  }

  // ---- epilogue: pure compute + store (noise already in regs) ----
  const float scale = 0.04419417382415922f;  // 1/sqrt(512)
  const float nstd  = 0.01f;
  #pragma unroll
  for (int m = 0; m < 4; ++m)
    #pragma unroll
    for (int r = 0; r < 4; ++r) {
      const size_t idx = obase + (size_t)(m * 16 + r) * NP;
      const float yr = accR[m][r] * scale + nrv[m][r] * nstd;
      const float yi = accI[m][r] * scale + niv[m][r] * nstd;
      outg[idx] = sqrtf(yr * yr + yi * yi);
    }
}

extern "C" void kernel_launch(void* const* d_in, const int* in_sizes, int n_in,
                              void* d_out, int out_size, void* d_ws, size_t ws_size,
                              hipStream_t stream) {
  const float* x  = (const float*)d_in[0];
  const float* Hr = (const float*)d_in[1];
  const float* Hi = (const float*)d_in[2];
  const float* nr = (const float*)d_in[3];
  const float* ni = (const float*)d_in[4];
  float* out = (float*)d_out;

  const size_t HN = (size_t)NBATCH * NC * NC;  // 2,097,152 elems per H array

  if (ws_size >= HN * 2 * sizeof(unsigned short)) {
    unsigned short* hrb = (unsigned short*)d_ws;
    unsigned short* hib = hrb + HN;
    hipLaunchKernelGGL(cvt_h_kernel, dim3(2048), dim3(256), 0, stream, Hr, Hi, hrb, hib);
    hipLaunchKernelGGL((rayleigh_main<1>), dim3(NBATCH * 2 * NBN), dim3(512), 0, stream,
                       x, Hr, Hi, hrb, hib, nr, ni, out);
  } else {
    hipLaunchKernelGGL((rayleigh_main<0>), dim3(NBATCH * 2 * NBN), dim3(512), 0, stream,
                       x, Hr, Hi, (const unsigned short*)nullptr, (const unsigned short*)nullptr,
                       nr, ni, out);
  }
}